// Round 1
// 251.878 us; speedup vs baseline: 1.0341x; 1.0341x over previous
//
#include <hip/hip_runtime.h>

// EdgeConv: B=32, N=2048, D=16, PCD=2, K_NN=16, FILTERS=64
// out[b,n,0:64]  = max(y_n, max_k y_{nn_k} - y_n) + b   where y = x@W (linearity)
// out[b,n,64:80] = x[b,n,:]
//
// R11: packed-f16 pass-1 selection (v_pk_min/max_f16 = 2 candidates/instr).
//   - pass 1: per-lane DUAL sorted-16 lists in v2f16 halves (even cands -> .x,
//     odd -> .y); f32 distance (fast fused form, pass-1-only) -> cvt_pkrtz (RTZ,
//     monotone) -> 31 packed ops / 2 cands vs 60 f32 ops before.
//   - threshold T_ub = succ2(RTZ(T16)) (>= 1 f16 ulp margin >> f32 formula
//     reassociation delta) guarantees T_ub > exact T strictly.
//   - pass 2: VERBATIM r9 distance; survivors d < T_ub appended per (q,split)
//     in index order (no atomics). ~16-17 survivors/query; cap 24/split.
//   - wave-0 finish per query: exact f32 T over survivors, then strict d<T +
//     d==T ties in split-asc/index-asc order == jax top_k lower-index-wins.
//     Selection SET bit-identical to the previous passing kernel.
//   - fused pool epilogue unchanged (idxL now u16).

#define B_  32
#define N_  2048
#define D_  16
#define F_  64
#define K_  16
#define OUTD (F_ + D_)   // 80
#define NQ  64           // queries per block
#define NS  4            // candidate splits (= waves per block)
#define SPLIT (N_ / NS)  // 512
#define CAP 24           // survivor cap per (query, split)

typedef _Float16 h2 __attribute__((ext_vector_type(2)));

static __device__ __forceinline__ h2 h2min(h2 a, h2 b) { return __builtin_elementwise_min(a, b); }
static __device__ __forceinline__ h2 h2max(h2 a, h2 b) { return __builtin_elementwise_max(a, b); }
static __device__ __forceinline__ _Float16 hmn(_Float16 a, _Float16 b) { return __builtin_elementwise_min(a, b); }
static __device__ __forceinline__ _Float16 hmx(_Float16 a, _Float16 b) { return __builtin_elementwise_max(a, b); }
static __device__ __forceinline__ unsigned short h2b(_Float16 h) { return __builtin_bit_cast(unsigned short, h); }
static __device__ __forceinline__ _Float16 b2h(unsigned short b) { return __builtin_bit_cast(_Float16, b); }

// insert ordered pair y0<=y1 into ascending sorted-16 (drop 2 largest) — exact
static __device__ __forceinline__ void pair_ins(_Float16 (&k)[16], _Float16 y0, _Float16 y1) {
#pragma unroll
    for (int j = 15; j >= 2; --j)
        k[j] = hmn(hmn(k[j], hmx(k[j - 1], y0)), hmx(k[j - 2], y1));
    k[1] = hmn(hmn(k[1], hmx(k[0], y0)), y1);
    k[0] = hmn(k[0], y0);
}

// r9-VERBATIM distance: pass 2 / finish must be bit-identical to prior kernel
static __device__ __forceinline__ float vdist(float2 qp, float sqn, float2 p, float sm) {
    float dot = __fmaf_rn(qp.y, p.y, __fmul_rn(qp.x, p.x));
    return __fsub_rn(__fadd_rn(sqn, sm), __fmul_rn(2.f, dot));
}

// ---------------- K1: Y = X * W  (bias folded into fused kernel) ------------
__global__ __launch_bounds__(256) void proj_kernel(const float* __restrict__ x,
                                                   const float* __restrict__ W,
                                                   float* __restrict__ Y) {
    __shared__ float Ws[D_ * F_];     // 4 KB
    __shared__ float xs[16][D_];      // 1 KB
    const int t = threadIdx.x;
    for (int i = t; i < D_ * F_; i += 256) Ws[i] = W[i];
    const int p0 = blockIdx.x * 16;
    ((float*)xs)[t] = x[(size_t)p0 * D_ + t];   // coalesced 1 KB
    __syncthreads();
    const int w = t >> 6, f = t & 63;
#pragma unroll
    for (int i = 0; i < 4; i++) {
        const int pw = w * 4 + i;
        float acc = 0.f;
#pragma unroll
        for (int d = 0; d < D_; d++) acc = fmaf(xs[pw][d], Ws[d * F_ + f], acc);
        Y[(size_t)(p0 + pw) * F_ + f] = acc;
    }
}

// ---------------- K2: exact 16-NN + fused conv-max-pool epilogue ------------
__global__ __launch_bounds__(256, 4) void knn_kernel(const float* __restrict__ x,
                                                     const float* __restrict__ bias,
                                                     const float* __restrict__ Y,
                                                     float* __restrict__ out) {
    __shared__ float2 pts[N_];                       // 16384 B
    __shared__ float  sqs[N_];                       // 8192 B
    // overlay: arr32 (6912 B) lives [barrier2, barrier3); survb [barrier3, ...)
    __shared__ __align__(16) char region[NS * NQ * CAP * 2];   // 12288 B
    __shared__ unsigned short idxL[NQ][18];          // 2304 B (stride 36 B: conflict-free)
    __shared__ int   scnt[NS][NQ];                   // 1024 B
    __shared__ float TubA[NQ];                       // 256 B   => 40448 B, 4 blocks/CU

    unsigned (*arr32)[NQ][9] = (unsigned (*)[NQ][9])region;                   // [NS-1][NQ][9]
    unsigned short (*survb)[NQ][CAP] = (unsigned short (*)[NQ][CAP])region;   // [NS][NQ][CAP]

    const int b = blockIdx.x >> 5;                 // 32 blocks per batch
    const int qbase = (blockIdx.x & 31) * NQ;
    const int t = threadIdx.x;
    const int s = t >> 6;                          // wave id = split id
    const int qi = t & 63;
    const int q = qbase + qi;

    const float* xb = x + (size_t)b * N_ * D_;
    for (int m = t; m < N_; m += 256) {
        float2 p = make_float2(xb[m * D_ + 0], xb[m * D_ + 1]);
        pts[m] = p;
        sqs[m] = __fadd_rn(__fmul_rn(p.x, p.x), __fmul_rn(p.y, p.y));
    }
    __syncthreads();                               // barrier 1

    const float2 qp = pts[q];
    const float sqn = sqs[q];
    const float n2x = -2.0f * qp.x, n2y = -2.0f * qp.y;   // exact (x2, negate)

    // ---- pass 1 (per split): packed-f16 dual sorted-16 over 512 cands
    h2 key2[16];
    const _Float16 hinf = b2h((unsigned short)0x7C00);
#pragma unroll
    for (int j = 0; j < 16; ++j) key2[j] = (h2){hinf, hinf};

    const int m0 = s * SPLIT, m1 = m0 + SPLIT;
#pragma unroll 4
    for (int m = m0; m < m1; m += 2) {
        float2 pa = pts[m];     float sa = sqs[m];
        float2 pb = pts[m + 1]; float sb = sqs[m + 1];
        float da = __fmaf_rn(n2y, pa.y, __fmaf_rn(n2x, pa.x, sqn + sa));
        float db = __fmaf_rn(n2y, pb.y, __fmaf_rn(n2x, pb.x, sqn + sb));
        h2 v = __builtin_bit_cast(h2, __builtin_amdgcn_cvt_pkrtz(da, db));
        // single-insert into both packed lists: reads OLD key2[j-1] (descending)
#pragma unroll
        for (int j = 15; j >= 1; --j)
            key2[j] = h2min(key2[j], h2max(key2[j - 1], v));
        key2[0] = h2min(key2[0], v);
    }

    // merge odd-list into even-list -> per-split sorted-16 (f16 scalar)
    _Float16 keyl[16];
#pragma unroll
    for (int j = 0; j < 16; ++j) keyl[j] = key2[j].x;
#pragma unroll
    for (int tt = 0; tt < 8; ++tt) pair_ins(keyl, key2[2 * tt].y, key2[2 * tt + 1].y);

    if (s > 0) {
#pragma unroll
        for (int tt = 0; tt < 8; ++tt)
            arr32[s - 1][qi][tt] =
                (unsigned)h2b(keyl[2 * tt]) | ((unsigned)h2b(keyl[2 * tt + 1]) << 16);
    }
    __syncthreads();                               // barrier 2

    // ---- merge (wave 0): global f16 16th-smallest -> safe upper bound T_ub
    if (s == 0) {
        for (int ss = 0; ss < NS - 1; ++ss) {
#pragma unroll
            for (int tt = 0; tt < 8; ++tt) {
                unsigned w32 = arr32[ss][qi][tt];
                pair_ins(keyl, b2h((unsigned short)(w32 & 0xffffu)),
                               b2h((unsigned short)(w32 >> 16)));
            }
        }
        // T16 = RTZ(exact 16th smallest of fast-d); +2 bits >= 1 f16 ulp margin
        float tub = (float)b2h((unsigned short)(h2b(keyl[15]) + 2));
        TubA[qi] = fmaxf(tub, 7e-5f);              // denormal-flush guard
    }
    __syncthreads();                               // barrier 3 (arr32 dead)

    // ---- pass 2 (all splits): exact f32 survivors d < T_ub, index-ascending
    const float Tub = TubA[qi];
    int sc = 0;
#pragma unroll 2
    for (int m = m0; m < m1; ++m) {
        float d = vdist(qp, sqn, pts[m], sqs[m]);
        if (d < Tub) { if (sc < CAP) survb[s][qi][sc] = (unsigned short)m; sc++; }
    }
    scnt[s][qi] = sc;
    __syncthreads();                               // barrier 4

    // ---- finish (wave 0, lane qi = query): exact T + ordered emit
    if (s == 0) {
        float key[16];
#pragma unroll
        for (int j = 0; j < 16; ++j) key[j] = INFINITY;
        for (int ss = 0; ss < NS; ++ss) {
            int n = scnt[ss][qi]; n = n < CAP ? n : CAP;
            for (int j = 0; j < n; ++j) {
                int m = (int)survb[ss][qi][j];
                float d = vdist(qp, sqn, pts[m], sqs[m]);
#pragma unroll
                for (int jj = 15; jj >= 1; --jj)
                    key[jj] = fminf(key[jj], fmaxf(key[jj - 1], d));
                key[0] = fminf(key[0], d);
            }
        }
        const float T = key[15];                   // exact global 16th smallest
        int w = 0;
        for (int ss = 0; ss < NS; ++ss) {          // strict d<T, global idx order
            int n = scnt[ss][qi]; n = n < CAP ? n : CAP;
            for (int j = 0; j < n; ++j) {
                int m = (int)survb[ss][qi][j];
                float d = vdist(qp, sqn, pts[m], sqs[m]);
                if (d < T && w < K_) idxL[qi][w++] = (unsigned short)m;
            }
        }
        for (int ss = 0; ss < NS && w < K_; ++ss) { // ties d==T, idx order
            int n = scnt[ss][qi]; n = n < CAP ? n : CAP;
            for (int j = 0; j < n && w < K_; ++j) {
                int m = (int)survb[ss][qi][j];
                float d = vdist(qp, sqn, pts[m], sqs[m]);
                if (d == T) idxL[qi][w++] = (unsigned short)m;
            }
        }
    }
    __syncthreads();                               // barrier 5

    // ---- fused pool epilogue: wave s handles queries s*16 .. s*16+15
    const int f = qi;                              // lane = filter (64)
    const float bf = bias[f];
    const float* Yb = Y + (size_t)b * N_ * F_;
    for (int i = 0; i < 16; i++) {
        const int qq = s * 16 + i;                 // local query id
        const int gq = qbase + qq;                 // batch-local point id
        const float yn = Yb[(size_t)gq * F_ + f];
        float M = -INFINITY;
#pragma unroll
        for (int k = 0; k < K_; k++) {
            int m = (int)idxL[qq][k];              // wave-uniform -> broadcast
            M = fmaxf(M, Yb[(size_t)m * F_ + f]);  // coalesced 256B row
        }
        const size_t pb = (size_t)b * N_ + gq;
        out[pb * OUTD + f] = fmaxf(yn, M - yn) + bf;
        if (f < D_) out[pb * OUTD + F_ + f] = xb[(size_t)gq * D_ + f];
    }
}

extern "C" void kernel_launch(void* const* d_in, const int* in_sizes, int n_in,
                              void* d_out, int out_size, void* d_ws, size_t ws_size,
                              hipStream_t stream) {
    const float* x    = (const float*)d_in[0];
    const float* W    = (const float*)d_in[1];
    const float* bias = (const float*)d_in[2];
    float* out = (float*)d_out;

    float* Y = (float*)d_ws;                       // 16.78 MB scratch

    proj_kernel<<<B_ * N_ / 16, 256, 0, stream>>>(x, W, Y);
    knn_kernel <<<B_ * (N_ / NQ), 256, 0, stream>>>(x, bias, Y, out);
}